// Round 3
// baseline (110.483 us; speedup 1.0000x reference)
//
#include <hip/hip_runtime.h>
#include <hip/hip_bf16.h>

// GATv2 on MI355X. G=80, N=1000, F=C=64, H=1, E=8000 (+N self loops). fp32 in/out.
// R13: keep R12's logit hoist  logit = SL6[s] + SR6[d] + sum_j 0.4*a_j*|v_j|
// but produce SL6/SR6 for FREE via MFMA instead of R12's shfl butterflies (which
// added ~2us of DS-pipe to BW-bound proj and regressed): a.(W^T x) = x.(W a), so
// u_l=0.6*(wl@att), u_r=0.6*(wr@att) become B-columns 128/129 (9th 16-col fragment,
// rest zeroed) -> +2 MFMA/sm (hidden under BW bound), lanes lm<2 store the dots.
// Agg: R12 math (a4-only channel work, sl gathered with u, bias sunk) but tail
// granularity reverted to R11-proven chunk-4.
// Ledger: harness ~90us immovable; proj ~7us ~= 41MB BW floor; agg ~9us.
// R12 post-mortem: hoist consumer right, producer (128 shfl/thread) mispriced.

#define GG 80
#define NN 1000
#define EE 8000
#define MM 80000           // G*N rows
#define PAD 40             // padded CSR row stride (ints): [0]=cnt, [1..cnt]=srcs
#define NEG_SLOPE 0.2f

typedef __attribute__((ext_vector_type(8))) short short8;    // 8 bf16 = 4 VGPRs
typedef __attribute__((ext_vector_type(4))) float floatx4;   // MFMA C/D

__device__ __forceinline__ unsigned short f2b(float f) {     // fp32 -> bf16 bits, RNE
    unsigned int u = __float_as_uint(f);
    unsigned int r = u + 0x7fffu + ((u >> 16) & 1u);
    return (unsigned short)(r >> 16);
}

// ---------------- Fused: blocks 0..312 = MFMA projection, block 313 = padded CSR ----------------
__global__ __launch_bounds__(256) void proj_csr_kernel(
    const float* __restrict__ x,
    const float* __restrict__ wl,
    const float* __restrict__ wr,
    const int* __restrict__ ei32,
    const float* __restrict__ att,
    unsigned short* __restrict__ XLt,
    unsigned short* __restrict__ XRt,
    float* __restrict__ SL6,
    float* __restrict__ SR6,
    int* __restrict__ list2)
{
    __shared__ __align__(16) unsigned short Wt[144 * 72];  // [col][k], pad 72; cols 128/129 = u_l/u_r
    __shared__ int cnt[1024];                              // csr: per-dst counters
    const int t = threadIdx.x;

    if (blockIdx.x == 313) {
        // ---- padded CSR: count via LDS atomics, write directly (no scan) ----
        int oddw = ei32[2 * t + 1];                        // idx<=511 in-bounds both widths
        const int stride = __any(oddw != 0) ? 1 : 2;       // int64(LE) => odd words zero

        for (int i = t; i < 1024; i += 256) cnt[i] = 0;
        __syncthreads();

        int dv[32], sv[32];
#pragma unroll
        for (int k = 0; k < 32; k++) {
            int e = t + (k << 8);
            dv[k] = (e < EE) ? ei32[(size_t)(EE + e) * stride] : -1;
        }
#pragma unroll
        for (int k = 0; k < 32; k++) {
            int e = t + (k << 8);
            sv[k] = (e < EE) ? ei32[(size_t)e * stride] : 0;
        }
#pragma unroll
        for (int k = 0; k < 32; k++) {
            if (dv[k] >= 0) {
                int pos = atomicAdd(&cnt[dv[k]], 1);
                if (pos < PAD - 2) list2[dv[k] * PAD + 1 + pos] = sv[k];
            }
        }
        __syncthreads();
        for (int n = t; n < NN; n += 256) {
            int c = min(cnt[n], PAD - 2);
            list2[n * PAD + 1 + c] = n;                    // self loop appended
            list2[n * PAD] = c + 1;                        // count
        }
        return;
    }

    // ---- MFMA projection (proven R4): wave handles 64 rows, N=128 (wl||wr) ----
    for (int idx = t; idx < 8192; idx += 256) {
        int half = idx >> 12;                 // 0: wl, 1: wr
        int k = (idx & 4095) >> 6;
        int c = idx & 63;
        float v = half ? wr[k * 64 + c] : wl[k * 64 + c];
        Wt[(c + half * 64) * 72 + k] = f2b(v);
    }
    // 9th fragment: cols 130..143 zero; col 128 = 0.6*(wl@att), col 129 = 0.6*(wr@att)
    for (int idx = t; idx < 14 * 72; idx += 256) Wt[130 * 72 + idx] = 0;
    if (t < 128) {
        const int k = t & 63;
        const float* w = (t < 64) ? wl : wr;
        float s = 0.f;
#pragma unroll
        for (int c = 0; c < 64; c++) s = fmaf(w[k * 64 + c], att[c], s);
        Wt[(128 + (t >> 6)) * 72 + k] = f2b(0.6f * s);
    }
    __syncthreads();

    const int wave = t >> 6;
    const int lane = t & 63;
    const int quad = lane >> 4;
    const int lm   = lane & 15;
    const int Rb   = (blockIdx.x * 4 + wave) * 64;

    short8 Bf[2][8];
    short8 Bf9[2];
#pragma unroll
    for (int ks = 0; ks < 2; ks++) {
#pragma unroll
        for (int sub = 0; sub < 8; sub++)
            Bf[ks][sub] = *(const short8*)(&Wt[(sub * 16 + lm) * 72 + ks * 32 + quad * 8]);
        Bf9[ks] = *(const short8*)(&Wt[(128 + lm) * 72 + ks * 32 + quad * 8]);
    }

    const float4* x4 = (const float4*)x;

#pragma unroll
    for (int sm = 0; sm < 4; sm++) {
        const int rbase = Rb + sm * 16;
        const int r  = rbase + lm;
        const int rc = (r < MM) ? r : (MM - 1);

        short8 Af[2];
#pragma unroll
        for (int ks = 0; ks < 2; ks++) {
            float4 p = x4[(size_t)rc * 16 + ks * 8 + quad * 2];
            float4 q = x4[(size_t)rc * 16 + ks * 8 + quad * 2 + 1];
            short8 a;
            a[0] = (short)f2b(p.x); a[1] = (short)f2b(p.y);
            a[2] = (short)f2b(p.z); a[3] = (short)f2b(p.w);
            a[4] = (short)f2b(q.x); a[5] = (short)f2b(q.y);
            a[6] = (short)f2b(q.z); a[7] = (short)f2b(q.w);
            Af[ks] = a;
        }

        floatx4 acc[8];
        floatx4 acc9 = (floatx4)(0.f);
#pragma unroll
        for (int sub = 0; sub < 8; sub++) acc[sub] = (floatx4)(0.f);
#pragma unroll
        for (int ks = 0; ks < 2; ks++) {
#pragma unroll
            for (int sub = 0; sub < 8; sub++)
                acc[sub] = __builtin_amdgcn_mfma_f32_16x16x32_bf16(Af[ks], Bf[ks][sub], acc[sub], 0, 0, 0);
            acc9 = __builtin_amdgcn_mfma_f32_16x16x32_bf16(Af[ks], Bf9[ks], acc9, 0, 0, 0);
        }

#pragma unroll
        for (int reg = 0; reg < 4; reg++) {
            int rr = rbase + quad * 4 + reg;
            if (rr < MM) {
                int g = rr / 1000;
                int n = rr - g * 1000;
                size_t ob = ((size_t)n * GG + g) * 64 + lm;
#pragma unroll
                for (int sub = 0; sub < 4; sub++)
                    XLt[ob + sub * 16] = f2b(acc[sub][reg]);
#pragma unroll
                for (int sub = 4; sub < 8; sub++)
                    XRt[ob + (sub - 4) * 16] = f2b(acc[sub][reg]);
                // 9th fragment cols 0/1 = node dots (free hoist for agg's logit)
                if (lm == 0)      SL6[(size_t)n * GG + g] = acc9[reg];
                else if (lm == 1) SR6[(size_t)n * GG + g] = acc9[reg];
            }
        }
    }
}

// ---------------- Aggregation: grid (1000, 5), block 128 thr = 16 graphs x 8 cgroups ----------------
// Header row read via uniform s_load (no LDS, no barrier). Gather: x16 uint4 ILP,
// chunk-of-4 scalar guards skip tail chunks (cnt block-uniform). Logit = hoisted
// linear part (SL6[s]+SR6[d]) + per-edge abs part. Softmax without max-shift
// (logits bounded) => associative weighted sum; within-chunk tail masked w=0.
__global__ __launch_bounds__(128) void agg_kernel(
    const unsigned short* __restrict__ XLt,
    const unsigned short* __restrict__ XRt,
    const int* __restrict__ list2,
    const float* __restrict__ att,
    const float* __restrict__ bias,
    const float* __restrict__ SL6,
    const float* __restrict__ SR6,
    float* __restrict__ out)
{
    const int t = threadIdx.x;
    const int d = blockIdx.x;
    const int g = blockIdx.y * 16 + (t >> 3);
    const int cg = t & 7;

    const int* hdr = list2 + d * PAD;                        // block-uniform base
    const int cnt = __builtin_amdgcn_readfirstlane(hdr[0]);  // SGPR -> scalar guards

    float xr[8], a4[8];
    {
        const uint4 u = *(const uint4*)(XRt + ((size_t)d * GG + g) * 64 + cg * 8);
        const unsigned int uw[4] = {u.x, u.y, u.z, u.w};
#pragma unroll
        for (int q = 0; q < 4; q++) {
            xr[2 * q + 0] = __uint_as_float(uw[q] << 16);
            xr[2 * q + 1] = __uint_as_float(uw[q] & 0xffff0000u);
        }
        const float4 a0 = *(const float4*)(att + cg * 8);
        const float4 a1 = *(const float4*)(att + cg * 8 + 4);
        const float aa[8] = {a0.x, a0.y, a0.z, a0.w, a1.x, a1.y, a1.z, a1.w};
#pragma unroll
        for (int j = 0; j < 8; j++) a4[j] = 0.4f * aa[j];    // |v| part only
    }
    const float sr6 = SR6[(size_t)d * GG + g];               // hoisted target dot

    float acc[8];
#pragma unroll
    for (int j = 0; j < 8; j++) acc[j] = 0.f;
    float dn = 0.f;

    for (int i = 0; i < cnt; i += 16) {
        uint4 u[16];
        float sl[16];
        // issue all valid-chunk gathers before any compute (no waitcnts between
        // guarded chunks -> full memory-level parallelism for the round)
#pragma unroll
        for (int c = 0; c < 4; c++) {
            if (i + 4 * c < cnt) {
#pragma unroll
                for (int e2 = 0; e2 < 4; e2++) {
                    const int idx = i + 4 * c + e2;
                    const int s = hdr[1 + ((idx < cnt) ? idx : 0)];   // uniform s_load
                    u[4 * c + e2] = *(const uint4*)(XLt + ((size_t)s * GG + g) * 64 + cg * 8);
                    sl[4 * c + e2] = SL6[(size_t)s * GG + g];
                }
            }
        }
#pragma unroll
        for (int c = 0; c < 4; c++) {
            if (i + 4 * c < cnt) {                                    // uniform -> s_cbranch
#pragma unroll
                for (int e2 = 0; e2 < 4; e2++) {
                    const int e = 4 * c + e2;
                    const unsigned int uw[4] = {u[e].x, u[e].y, u[e].z, u[e].w};
                    float xf[8];
#pragma unroll
                    for (int q = 0; q < 4; q++) {
                        xf[2 * q]     = __uint_as_float(uw[q] << 16);
                        xf[2 * q + 1] = __uint_as_float(uw[q] & 0xffff0000u);
                    }
                    float p = 0.f;
#pragma unroll
                    for (int j = 0; j < 8; j++) {
                        const float v = xf[j] + xr[j];
                        p = fmaf(a4[j], fabsf(v), p);   // |v| = free VOP3 modifier
                    }
                    p += __shfl_xor(p, 1, 64);
                    p += __shfl_xor(p, 2, 64);
                    p += __shfl_xor(p, 4, 64);
                    p += sl[e] + sr6;                   // hoisted linear part
                    const float w = (i + e < cnt) ? __expf(p) : 0.f;  // within-chunk mask
                    dn += w;
#pragma unroll
                    for (int j = 0; j < 8; j++) acc[j] = fmaf(w, xf[j], acc[j]);
                }
            }
        }
    }

    const float inv = 1.f / dn;
    const float4 b0 = *(const float4*)(bias + cg * 8);       // sunk: not live in loop
    const float4 b1 = *(const float4*)(bias + cg * 8 + 4);
    float4 r0, r1;
    r0.x = fmaf(acc[0], inv, b0.x);
    r0.y = fmaf(acc[1], inv, b0.y);
    r0.z = fmaf(acc[2], inv, b0.z);
    r0.w = fmaf(acc[3], inv, b0.w);
    r1.x = fmaf(acc[4], inv, b1.x);
    r1.y = fmaf(acc[5], inv, b1.y);
    r1.z = fmaf(acc[6], inv, b1.z);
    r1.w = fmaf(acc[7], inv, b1.w);
    float* po = out + ((size_t)g * NN + d) * 64 + cg * 8;
    *(float4*)po = r0;
    *(float4*)(po + 4) = r1;
}

extern "C" void kernel_launch(void* const* d_in, const int* in_sizes, int n_in,
                              void* d_out, int out_size, void* d_ws, size_t ws_size,
                              hipStream_t stream) {
    const float* x    = (const float*)d_in[0];
    const int*   ei   = (const int*)d_in[1];
    const float* wl   = (const float*)d_in[2];
    const float* wr   = (const float*)d_in[3];
    const float* att  = (const float*)d_in[4];
    const float* bias = (const float*)d_in[5];
    float* out = (float*)d_out;

    char* ws = (char*)d_ws;
    int* list2 = (int*)ws;                                   // 1000*40 ints = 160 KB
    unsigned short* XLt = (unsigned short*)(ws + 262144);    // [N][G][64] bf16 = 10.24 MB
    unsigned short* XRt = XLt + (size_t)NN * GG * 64;        // + 10.24 MB
    float* SL6 = (float*)(ws + 262144 + 2 * (size_t)NN * GG * 64 * 2);  // [N][G] f32 = 320 KB
    float* SR6 = SL6 + (size_t)NN * GG;                                  // + 320 KB

    hipLaunchKernelGGL(proj_csr_kernel, dim3(314), dim3(256), 0, stream,
                       x, wl, wr, ei, att, XLt, XRt, SL6, SR6, list2);
    hipLaunchKernelGGL(agg_kernel, dim3(NN, 5), dim3(128), 0, stream,
                       XLt, XRt, list2, att, bias, SL6, SR6, out);
}

// Round 4
// 106.423 us; speedup vs baseline: 1.0381x; 1.0381x over previous
//
#include <hip/hip_runtime.h>
#include <hip/hip_bf16.h>

// GATv2 on MI355X. G=80, N=1000, F=C=64, H=1, E=8000 (+N self loops). fp32 in/out.
// R14 = R11 revert (best measured: 106.6us) + bias-load sunk to epilogue (only
// zero-risk piece of R12). R12/R13 post-mortem: hoisting the linear logit part
// (SL6[s]+SR6[d]) traded 8 fma/edge (VALU, hidden) for 1 extra gather/edge in the
// latency-critical VMEM clause -> +3-4us both times, regardless of producer cost.
// Lesson: in agg, gather-clause VMEM issues are the currency; per-edge VALU is free.
// R11 structure: chunk-4 uniform tail guards (cnt block-uniform, avg 9 -> ~10.4
// computed edges vs 16), leaky(v)=0.6v+0.4|v| with att folded (a6/a4, |v| free
// VOP3 mod), header row via uniform s_load (cnt in SGPR -> s_cbranch guards).
// Ledger: harness ~90us immovable (45us ws-poison fill at ~75% HBM peak + out
// poison + restores + gaps); proj ~7us ~= its 41MB BW floor; agg ~9.5us ~= latency
// floor (2 dependent cold rounds + ~4us VALU + 20.5MB out write at ~3.3us).

#define GG 80
#define NN 1000
#define EE 8000
#define MM 80000           // G*N rows
#define PAD 40             // padded CSR row stride (ints): [0]=cnt, [1..cnt]=srcs
#define NEG_SLOPE 0.2f

typedef __attribute__((ext_vector_type(8))) short short8;    // 8 bf16 = 4 VGPRs
typedef __attribute__((ext_vector_type(4))) float floatx4;   // MFMA C/D

__device__ __forceinline__ unsigned short f2b(float f) {     // fp32 -> bf16 bits, RNE
    unsigned int u = __float_as_uint(f);
    unsigned int r = u + 0x7fffu + ((u >> 16) & 1u);
    return (unsigned short)(r >> 16);
}

// ---------------- Fused: blocks 0..312 = MFMA projection, block 313 = padded CSR ----------------
__global__ __launch_bounds__(256) void proj_csr_kernel(
    const float* __restrict__ x,
    const float* __restrict__ wl,
    const float* __restrict__ wr,
    const int* __restrict__ ei32,
    unsigned short* __restrict__ XLt,
    unsigned short* __restrict__ XRt,
    int* __restrict__ list2)
{
    __shared__ __align__(16) unsigned short Wt[128 * 72];  // proj: W [col][k], pad 72
    __shared__ int cnt[1024];                              // csr: per-dst counters
    const int t = threadIdx.x;

    if (blockIdx.x == 313) {
        // ---- padded CSR: count via LDS atomics, write directly (no scan) ----
        int oddw = ei32[2 * t + 1];                        // idx<=511 in-bounds both widths
        const int stride = __any(oddw != 0) ? 1 : 2;       // int64(LE) => odd words zero

        for (int i = t; i < 1024; i += 256) cnt[i] = 0;
        __syncthreads();

        int dv[32], sv[32];
#pragma unroll
        for (int k = 0; k < 32; k++) {
            int e = t + (k << 8);
            dv[k] = (e < EE) ? ei32[(size_t)(EE + e) * stride] : -1;
        }
#pragma unroll
        for (int k = 0; k < 32; k++) {
            int e = t + (k << 8);
            sv[k] = (e < EE) ? ei32[(size_t)e * stride] : 0;
        }
#pragma unroll
        for (int k = 0; k < 32; k++) {
            if (dv[k] >= 0) {
                int pos = atomicAdd(&cnt[dv[k]], 1);
                if (pos < PAD - 2) list2[dv[k] * PAD + 1 + pos] = sv[k];
            }
        }
        __syncthreads();
        for (int n = t; n < NN; n += 256) {
            int c = min(cnt[n], PAD - 2);
            list2[n * PAD + 1 + c] = n;                    // self loop appended
            list2[n * PAD] = c + 1;                        // count
        }
        return;
    }

    // ---- MFMA projection (proven R4): wave handles 64 rows, N=128 (wl||wr) ----
    for (int idx = t; idx < 8192; idx += 256) {
        int half = idx >> 12;                 // 0: wl, 1: wr
        int k = (idx & 4095) >> 6;
        int c = idx & 63;
        float v = half ? wr[k * 64 + c] : wl[k * 64 + c];
        Wt[(c + half * 64) * 72 + k] = f2b(v);
    }
    __syncthreads();

    const int wave = t >> 6;
    const int lane = t & 63;
    const int quad = lane >> 4;
    const int lm   = lane & 15;
    const int Rb   = (blockIdx.x * 4 + wave) * 64;

    short8 Bf[2][8];
#pragma unroll
    for (int ks = 0; ks < 2; ks++)
#pragma unroll
        for (int sub = 0; sub < 8; sub++)
            Bf[ks][sub] = *(const short8*)(&Wt[(sub * 16 + lm) * 72 + ks * 32 + quad * 8]);

    const float4* x4 = (const float4*)x;

#pragma unroll
    for (int sm = 0; sm < 4; sm++) {
        const int rbase = Rb + sm * 16;
        const int r  = rbase + lm;
        const int rc = (r < MM) ? r : (MM - 1);

        short8 Af[2];
#pragma unroll
        for (int ks = 0; ks < 2; ks++) {
            float4 p = x4[(size_t)rc * 16 + ks * 8 + quad * 2];
            float4 q = x4[(size_t)rc * 16 + ks * 8 + quad * 2 + 1];
            short8 a;
            a[0] = (short)f2b(p.x); a[1] = (short)f2b(p.y);
            a[2] = (short)f2b(p.z); a[3] = (short)f2b(p.w);
            a[4] = (short)f2b(q.x); a[5] = (short)f2b(q.y);
            a[6] = (short)f2b(q.z); a[7] = (short)f2b(q.w);
            Af[ks] = a;
        }

        floatx4 acc[8];
#pragma unroll
        for (int sub = 0; sub < 8; sub++) acc[sub] = (floatx4)(0.f);
#pragma unroll
        for (int ks = 0; ks < 2; ks++)
#pragma unroll
            for (int sub = 0; sub < 8; sub++)
                acc[sub] = __builtin_amdgcn_mfma_f32_16x16x32_bf16(Af[ks], Bf[ks][sub], acc[sub], 0, 0, 0);

#pragma unroll
        for (int reg = 0; reg < 4; reg++) {
            int rr = rbase + quad * 4 + reg;
            if (rr < MM) {
                int g = rr / 1000;
                int n = rr - g * 1000;
                size_t ob = ((size_t)n * GG + g) * 64 + lm;
#pragma unroll
                for (int sub = 0; sub < 4; sub++)
                    XLt[ob + sub * 16] = f2b(acc[sub][reg]);
#pragma unroll
                for (int sub = 4; sub < 8; sub++)
                    XRt[ob + (sub - 4) * 16] = f2b(acc[sub][reg]);
            }
        }
    }
}

// ---------------- Aggregation: grid (1000, 5), block 128 thr = 16 graphs x 8 cgroups ----------------
// Header row read via uniform s_load (no LDS, no barrier). Gather: x16 uint4 ILP,
// chunk-of-4 scalar guards skip tail chunks (cnt block-uniform). Softmax without
// max-shift (logits bounded) => associative weighted sum; within-chunk tail masked w=0.
__global__ __launch_bounds__(128) void agg_kernel(
    const unsigned short* __restrict__ XLt,
    const unsigned short* __restrict__ XRt,
    const int* __restrict__ list2,
    const float* __restrict__ att,
    const float* __restrict__ bias,
    float* __restrict__ out)
{
    const int t = threadIdx.x;
    const int d = blockIdx.x;
    const int g = blockIdx.y * 16 + (t >> 3);
    const int cg = t & 7;

    const int* hdr = list2 + d * PAD;                        // block-uniform base
    const int cnt = __builtin_amdgcn_readfirstlane(hdr[0]);  // SGPR -> scalar guards

    float xr[8], a6[8], a4[8];
    {
        const uint4 u = *(const uint4*)(XRt + ((size_t)d * GG + g) * 64 + cg * 8);
        const unsigned int uw[4] = {u.x, u.y, u.z, u.w};
#pragma unroll
        for (int q = 0; q < 4; q++) {
            xr[2 * q + 0] = __uint_as_float(uw[q] << 16);
            xr[2 * q + 1] = __uint_as_float(uw[q] & 0xffff0000u);
        }
        // leaky_relu(v) = max(v,0)+0.2*min(v,0) == 0.6*v + 0.4*|v|; fold att weight.
        const float4 a0 = *(const float4*)(att + cg * 8);
        const float4 a1 = *(const float4*)(att + cg * 8 + 4);
        const float aa[8] = {a0.x, a0.y, a0.z, a0.w, a1.x, a1.y, a1.z, a1.w};
#pragma unroll
        for (int j = 0; j < 8; j++) {
            a6[j] = 0.6f * aa[j];
            a4[j] = 0.4f * aa[j];
        }
    }

    float acc[8];
#pragma unroll
    for (int j = 0; j < 8; j++) acc[j] = 0.f;
    float dn = 0.f;

    for (int i = 0; i < cnt; i += 16) {
        uint4 u[16];
        // issue all valid-chunk gathers before any compute (no waitcnts between
        // guarded chunks -> full memory-level parallelism for the round)
#pragma unroll
        for (int c = 0; c < 4; c++) {
            if (i + 4 * c < cnt) {
#pragma unroll
                for (int e2 = 0; e2 < 4; e2++) {
                    const int idx = i + 4 * c + e2;
                    const int s = hdr[1 + ((idx < cnt) ? idx : 0)];   // uniform s_load
                    u[4 * c + e2] = *(const uint4*)(XLt + ((size_t)s * GG + g) * 64 + cg * 8);
                }
            }
        }
#pragma unroll
        for (int c = 0; c < 4; c++) {
            if (i + 4 * c < cnt) {                                    // uniform -> s_cbranch
#pragma unroll
                for (int e2 = 0; e2 < 4; e2++) {
                    const int e = 4 * c + e2;
                    const unsigned int uw[4] = {u[e].x, u[e].y, u[e].z, u[e].w};
                    float xf[8];
#pragma unroll
                    for (int q = 0; q < 4; q++) {
                        xf[2 * q]     = __uint_as_float(uw[q] << 16);
                        xf[2 * q + 1] = __uint_as_float(uw[q] & 0xffff0000u);
                    }
                    float p = 0.f;
#pragma unroll
                    for (int j = 0; j < 8; j++) {
                        const float v = xf[j] + xr[j];
                        p = fmaf(a6[j], v, p);
                        p = fmaf(a4[j], fabsf(v), p);   // |v| = free VOP3 modifier
                    }
                    p += __shfl_xor(p, 1, 64);
                    p += __shfl_xor(p, 2, 64);
                    p += __shfl_xor(p, 4, 64);
                    const float w = (i + e < cnt) ? __expf(p) : 0.f;  // within-chunk mask
                    dn += w;
#pragma unroll
                    for (int j = 0; j < 8; j++) acc[j] = fmaf(w, xf[j], acc[j]);
                }
            }
        }
    }

    const float inv = 1.f / dn;
    const float4 b0 = *(const float4*)(bias + cg * 8);       // sunk: not live in loop
    const float4 b1 = *(const float4*)(bias + cg * 8 + 4);
    float4 r0, r1;
    r0.x = fmaf(acc[0], inv, b0.x);
    r0.y = fmaf(acc[1], inv, b0.y);
    r0.z = fmaf(acc[2], inv, b0.z);
    r0.w = fmaf(acc[3], inv, b0.w);
    r1.x = fmaf(acc[4], inv, b1.x);
    r1.y = fmaf(acc[5], inv, b1.y);
    r1.z = fmaf(acc[6], inv, b1.z);
    r1.w = fmaf(acc[7], inv, b1.w);
    float* po = out + ((size_t)g * NN + d) * 64 + cg * 8;
    *(float4*)po = r0;
    *(float4*)(po + 4) = r1;
}

extern "C" void kernel_launch(void* const* d_in, const int* in_sizes, int n_in,
                              void* d_out, int out_size, void* d_ws, size_t ws_size,
                              hipStream_t stream) {
    const float* x    = (const float*)d_in[0];
    const int*   ei   = (const int*)d_in[1];
    const float* wl   = (const float*)d_in[2];
    const float* wr   = (const float*)d_in[3];
    const float* att  = (const float*)d_in[4];
    const float* bias = (const float*)d_in[5];
    float* out = (float*)d_out;

    char* ws = (char*)d_ws;
    int* list2 = (int*)ws;                                   // 1000*40 ints = 160 KB
    unsigned short* XLt = (unsigned short*)(ws + 262144);    // [N][G][64] bf16 = 10.24 MB
    unsigned short* XRt = XLt + (size_t)NN * GG * 64;        // + 10.24 MB

    hipLaunchKernelGGL(proj_csr_kernel, dim3(314), dim3(256), 0, stream,
                       x, wl, wr, ei, XLt, XRt, list2);
    hipLaunchKernelGGL(agg_kernel, dim3(NN, 5), dim3(128), 0, stream,
                       XLt, XRt, list2, att, bias, out);
}